// Round 21
// baseline (201.446 us; speedup 1.0000x reference)
//
#include <hip/hip_runtime.h>

#define NN 100000
#define NE 1600000
#define IC 128
#define HID 32
#define NB 782           // buckets of 128 nodes
#define BCAP 2560        // padded bucket capacity (mean 2048, sigma~45)
#define EB 4096          // edges per binning block
#define NBA 391          // ceil(NE/EB)
#define NPJ 782          // ceil(NN/128) proj blocks (128 nodes each, 8 waves)
#define CPAD 16          // gcursor padding: one 64B line per bucket (kills same-line atomic serialization)

typedef unsigned short ushort_t;
typedef __attribute__((ext_vector_type(8))) short short8v;
typedef __attribute__((ext_vector_type(4))) float f32x4;

__device__ __forceinline__ ushort_t f2bf(float x) {
    unsigned u = __float_as_uint(x);
    unsigned r = (u + 0x7fffu + ((u >> 16) & 1u)) >> 16;   // RNE
    return (ushort_t)r;
}
__device__ __forceinline__ float bf2f(ushort_t b) {
    return __uint_as_float(((unsigned)b) << 16);
}

__device__ __forceinline__ int edge_at(const void* ei, int i64f, long long idx) {
    return i64f ? (int)((const long long*)ei)[idx] : ((const int*)ei)[idx];
}

// 8-deep independent-load gather step (lane l owns features 4l..4l+3)
#define GATHER8(SRC, Y)                                                            \
    for (; p + 8 <= end; p += 8) {                                                 \
        int s0 = SRC[p],     s1 = SRC[p + 1], s2 = SRC[p + 2], s3 = SRC[p + 3];    \
        int s4 = SRC[p + 4], s5 = SRC[p + 5], s6 = SRC[p + 6], s7 = SRC[p + 7];    \
        ushort4 u0 = *(const ushort4*)&Y[(size_t)s0 * 32 + l * 4];                 \
        ushort4 u1 = *(const ushort4*)&Y[(size_t)s1 * 32 + l * 4];                 \
        ushort4 u2 = *(const ushort4*)&Y[(size_t)s2 * 32 + l * 4];                 \
        ushort4 u3 = *(const ushort4*)&Y[(size_t)s3 * 32 + l * 4];                 \
        ushort4 u4 = *(const ushort4*)&Y[(size_t)s4 * 32 + l * 4];                 \
        ushort4 u5 = *(const ushort4*)&Y[(size_t)s5 * 32 + l * 4];                 \
        ushort4 u6 = *(const ushort4*)&Y[(size_t)s6 * 32 + l * 4];                 \
        ushort4 u7 = *(const ushort4*)&Y[(size_t)s7 * 32 + l * 4];                 \
        ax += bf2f(u0.x); ay += bf2f(u0.y); az += bf2f(u0.z); aw += bf2f(u0.w);    \
        bx += bf2f(u1.x); by += bf2f(u1.y); bz += bf2f(u1.z); bw += bf2f(u1.w);    \
        cx += bf2f(u2.x); cy += bf2f(u2.y); cz += bf2f(u2.z); cw += bf2f(u2.w);    \
        dx += bf2f(u3.x); dy += bf2f(u3.y); dz += bf2f(u3.z); dw += bf2f(u3.w);    \
        ax += bf2f(u4.x); ay += bf2f(u4.y); az += bf2f(u4.z); aw += bf2f(u4.w);    \
        bx += bf2f(u5.x); by += bf2f(u5.y); bz += bf2f(u5.z); bw += bf2f(u5.w);    \
        cx += bf2f(u6.x); cy += bf2f(u6.y); cz += bf2f(u6.z); cw += bf2f(u6.w);    \
        dx += bf2f(u7.x); dy += bf2f(u7.y); dz += bf2f(u7.z); dw += bf2f(u7.w);    \
    }                                                                              \
    for (; p + 4 <= end; p += 4) {                                                 \
        int s0 = SRC[p], s1 = SRC[p + 1], s2 = SRC[p + 2], s3 = SRC[p + 3];        \
        ushort4 u0 = *(const ushort4*)&Y[(size_t)s0 * 32 + l * 4];                 \
        ushort4 u1 = *(const ushort4*)&Y[(size_t)s1 * 32 + l * 4];                 \
        ushort4 u2 = *(const ushort4*)&Y[(size_t)s2 * 32 + l * 4];                 \
        ushort4 u3 = *(const ushort4*)&Y[(size_t)s3 * 32 + l * 4];                 \
        ax += bf2f(u0.x); ay += bf2f(u0.y); az += bf2f(u0.z); aw += bf2f(u0.w);    \
        bx += bf2f(u1.x); by += bf2f(u1.y); bz += bf2f(u1.z); bw += bf2f(u1.w);    \
        cx += bf2f(u2.x); cy += bf2f(u2.y); cz += bf2f(u2.z); cw += bf2f(u2.w);    \
        dx += bf2f(u3.x); dy += bf2f(u3.y); dz += bf2f(u3.z); dw += bf2f(u3.w);    \
    }                                                                              \
    for (; p < end; p++) {                                                         \
        ushort4 u0 = *(const ushort4*)&Y[(size_t)SRC[p] * 32 + l * 4];             \
        ax += bf2f(u0.x); ay += bf2f(u0.y); az += bf2f(u0.z); aw += bf2f(u0.w);    \
    }

// ---------------- setup: detect + folded weights + padded cursors + w1a MFMA B-fragments ----------------
__global__ __launch_bounds__(1024) void setup_kernel(const void* ei, const float* __restrict__ w1a,
                                                     const float* __restrict__ w1b, const float* __restrict__ b1b,
                                                     const float* __restrict__ w2a, const float* __restrict__ w2b,
                                                     const float* __restrict__ b2b, const float* __restrict__ w3,
                                                     int* flag, int* gcursor,
                                                     float* Wc, float* bc1, float* wc2, float* c0,
                                                     ushort_t* Bfrag) {
    int t = threadIdx.x;
    if (blockIdx.x == 1) {
        for (int i = t; i < NB * CPAD; i += 1024) gcursor[i] = 0;
        return;
    }
    if (blockIdx.x == 2) {
        if (t < 512) {
            int s = t >> 7, u = (t >> 6) & 1, l = t & 63;
            int krow = s * 32 + (l >> 4) * 8;
            int col = u * 16 + (l & 15);
            #pragma unroll
            for (int j = 0; j < 8; j++)
                Bfrag[t * 8 + j] = f2bf(w1a[(krow + j) * 32 + col]);
        }
        return;
    }
    if (t < 64) {
        const long long* p = (const long long*)ei;
        long long v = p[t];
        unsigned long long bad = __ballot(v < 0 || v >= NN);
        if (t == 0) *flag = (bad == 0ull) ? 1 : 0;
    }
    int k = t >> 5, j = t & 31;
    float acc = 0.f;
    for (int m = 0; m < HID; m++) acc += w1b[k * HID + m] * w2a[m * HID + j];
    Wc[k * HID + j] = acc;
    if (t < 32) {
        float a = 0.f;
        for (int m = 0; m < HID; m++) a += b1b[m] * w2a[m * HID + t];
        bc1[t] = a;
    } else if (t < 64) {
        int kk = t - 32;
        float a = 0.f;
        for (int jj = 0; jj < HID; jj++) a += w2b[kk * HID + jj] * w3[jj];
        wc2[kk] = a;
    } else if (t == 64) {
        float a = 0.f;
        for (int jj = 0; jj < HID; jj++) a += b2b[jj] * w3[jj];
        *c0 = a;
    }
}

// ---------------- direct-scatter bin (padded cursor lines, zero LDS) + MFMA proj merged ----------------
// r19 calibration: same-line L2 atomic ~28cy. One 64B line per bucket -> per-line makespan
// 2046 x 28cy = 24us, lines parallel across L2 slices. No hist, no reserve, no LDS.
__global__ __launch_bounds__(512) void proj_bin_kernel(const float* __restrict__ x,
                                                       const ushort_t* __restrict__ Bfrag,
                                                       ushort_t* __restrict__ y1,
                                                       const void* ei, const int* flag,
                                                       int* gcursor,
                                                       unsigned int* __restrict__ binned) {
    int t = threadIdx.x;

    if (blockIdx.x < NBA) {
        int i64f = *flag;
        long long ebase = (long long)blockIdx.x * EB;
        #pragma unroll
        for (int q = 0; q < EB / 512; q++) {
            long long e = ebase + q * 512 + t;
            if (e < NE) {
                int s = edge_at(ei, i64f, e);
                int d = edge_at(ei, i64f, NE + e);
                int b = d >> 7;
                int pos = atomicAdd(&gcursor[b * CPAD], 1);
                binned[(size_t)b * BCAP + pos] = ((unsigned)s << 7) | (unsigned)(d & 127);
            }
        }
    } else {
        // ---- MFMA proj: y1 = bf16(x @ w1a). 8 waves x 16 nodes = 128 nodes/block ----
        int pb = blockIdx.x - NBA;
        int wv = t >> 6, l = t & 63;
        int base = pb * 128 + wv * 16;
        int row = l & 15;
        int kg = l >> 4;                 // 0..3
        size_t m = (size_t)(base + row);
        if (m >= NN) m = NN - 1;         // clamp (last block): result discarded
        const float* xr = x + m * 128 + kg * 8;

        f32x4 acc0 = {0.f, 0.f, 0.f, 0.f};
        f32x4 acc1 = {0.f, 0.f, 0.f, 0.f};
        #pragma unroll
        for (int s = 0; s < 4; s++) {
            float4 xa = *(const float4*)(xr + s * 32);
            float4 xb = *(const float4*)(xr + s * 32 + 4);
            short8v af;
            af[0] = (short)f2bf(xa.x); af[1] = (short)f2bf(xa.y);
            af[2] = (short)f2bf(xa.z); af[3] = (short)f2bf(xa.w);
            af[4] = (short)f2bf(xb.x); af[5] = (short)f2bf(xb.y);
            af[6] = (short)f2bf(xb.z); af[7] = (short)f2bf(xb.w);
            short8v b0 = *(const short8v*)&Bfrag[((s * 2 + 0) * 64 + l) * 8];
            short8v b1 = *(const short8v*)&Bfrag[((s * 2 + 1) * 64 + l) * 8];
            acc0 = __builtin_amdgcn_mfma_f32_16x16x32_bf16(af, b0, acc0, 0, 0, 0);
            acc1 = __builtin_amdgcn_mfma_f32_16x16x32_bf16(af, b1, acc1, 0, 0, 0);
        }
        int col = l & 15;
        #pragma unroll
        for (int r = 0; r < 4; r++) {
            int node = base + kg * 4 + r;
            if (node < NN) {
                y1[(size_t)node * 32 + col]      = f2bf(acc0[r]);
                y1[(size_t)node * 32 + 16 + col] = f2bf(acc1[r]);
            }
        }
    }
}

// ---------------- csr_agg1: per-bucket CSR sort + layer-1 gather + fused MLP, 512 thr ----------------
__global__ __launch_bounds__(512) void csr_agg1_kernel(const unsigned int* __restrict__ binned,
                                                       const int* __restrict__ gcursor,
                                                       const ushort_t* __restrict__ y1,
                                                       const float* __restrict__ b1a,
                                                       const float* __restrict__ Wc,
                                                       const float* __restrict__ bc1,
                                                       int* __restrict__ rowbeg,
                                                       int* __restrict__ rowend,
                                                       int* __restrict__ esrc,
                                                       ushort_t* __restrict__ y2) {
    __shared__ int cnt[128];
    __shared__ int sc[128];
    __shared__ int cur[128];
    __shared__ int esl[BCAP];          // 10,240 B
    __shared__ float Wl[HID * HID];    //  4,096 B
    __shared__ float ul[128 * 36];     // 18,432 B   (total ~34.3 KB -> 4 blocks/CU)
    int t = threadIdx.x;
    int b = blockIdx.x;
    int n_edges = gcursor[b * CPAD];
    int bbase = b * BCAP;

    Wl[t] = Wc[t];
    Wl[512 + t] = Wc[512 + t];
    if (t < 128) cnt[t] = 0;
    __syncthreads();
    for (int p = t; p < n_edges; p += 512)
        atomicAdd(&cnt[binned[bbase + p] & 127], 1);
    __syncthreads();
    if (t < 128) sc[t] = cnt[t];
    __syncthreads();
    for (int off = 1; off < 128; off <<= 1) {
        int a = 0;
        if (t < 128 && t >= off) a = sc[t - off];
        __syncthreads();
        if (t < 128) sc[t] += a;
        __syncthreads();
    }
    if (t < 128) {
        int excl = sc[t] - cnt[t];
        cur[t] = excl;
        int gn = (b << 7) + t;
        if (gn < NN) { rowbeg[gn] = bbase + excl; rowend[gn] = bbase + excl + cnt[t]; }
    }
    __syncthreads();
    for (int p = t; p < n_edges; p += 512) {
        unsigned wv = binned[bbase + p];
        int dl = wv & 127;
        int pos = atomicAdd(&cur[dl], 1);
        int src = (int)(wv >> 7);
        esl[pos] = src;
        esrc[bbase + pos] = src;       // persist for layers 2/3
    }
    __syncthreads();

    // ---- phase 2: gather + relu, 2 chunks of 64 nodes ----
    int gg = t >> 3;                   // 0..63
    int l = t & 7;
    #pragma unroll
    for (int chunk = 0; chunk < 2; chunk++) {
        int g = chunk * 64 + gg;
        int gn = (b << 7) + g;
        int beg = sc[g] - cnt[g];
        int end = sc[g];
        float ax = 0.f, ay = 0.f, az = 0.f, aw = 0.f;
        float bx = 0.f, by = 0.f, bz = 0.f, bw = 0.f;
        float cx = 0.f, cy = 0.f, cz = 0.f, cw = 0.f;
        float dx = 0.f, dy = 0.f, dz = 0.f, dw = 0.f;
        int p = beg;
        GATHER8(esl, y1)
        if (gn < NN) {
            ushort4 us = *(const ushort4*)&y1[(size_t)gn * 32 + l * 4];   // self (eps=0)
            float u0 = (ax + bx) + (cx + dx) + bf2f(us.x) + b1a[l * 4 + 0];
            float u1 = (ay + by) + (cy + dy) + bf2f(us.y) + b1a[l * 4 + 1];
            float u2 = (az + bz) + (cz + dz) + bf2f(us.z) + b1a[l * 4 + 2];
            float u3 = (aw + bw) + (cw + dw) + bf2f(us.w) + b1a[l * 4 + 3];
            u0 = u0 > 0.f ? u0 : 0.f;
            u1 = u1 > 0.f ? u1 : 0.f;
            u2 = u2 > 0.f ? u2 : 0.f;
            u3 = u3 > 0.f ? u3 : 0.f;
            *(float4*)&ul[g * 36 + l * 4] = make_float4(u0, u1, u2, u3);
        }
    }
    __syncthreads();
    #pragma unroll
    for (int chunk = 0; chunk < 2; chunk++) {
        int g = chunk * 64 + gg;
        int gn = (b << 7) + g;
        if (gn < NN) {
            float4 acc = *(const float4*)&bc1[l * 4];
            #pragma unroll
            for (int k = 0; k < HID; k++) {
                float uk = ul[g * 36 + k];
                float4 wv = *(const float4*)&Wl[k * HID + l * 4];
                acc.x += uk * wv.x; acc.y += uk * wv.y;
                acc.z += uk * wv.z; acc.w += uk * wv.w;
            }
            ushort4 ov;
            ov.x = f2bf(acc.x); ov.y = f2bf(acc.y); ov.z = f2bf(acc.z); ov.w = f2bf(acc.w);
            *(ushort4*)&y2[(size_t)gn * 32 + l * 4] = ov;
        }
    }
}

// ---------------- agg_mlp2: 8-lane gather (8-deep ILP) + fused relu/dot -> sbuf ----------------
__global__ __launch_bounds__(256) void agg_mlp2_kernel(const ushort_t* __restrict__ y2,
                                                       const int* __restrict__ rowbeg,
                                                       const int* __restrict__ rowend,
                                                       const int* __restrict__ esrc,
                                                       const float* __restrict__ b2a,
                                                       const float* __restrict__ wc2,
                                                       const float* __restrict__ c0,
                                                       float* __restrict__ sbuf) {
    int t = threadIdx.x;
    int g = t >> 3;
    int l = t & 7;
    int n = blockIdx.x * 32 + g;

    int beg = rowbeg[n], end = rowend[n];
    float ax = 0.f, ay = 0.f, az = 0.f, aw = 0.f;
    float bx = 0.f, by = 0.f, bz = 0.f, bw = 0.f;
    float cx = 0.f, cy = 0.f, cz = 0.f, cw = 0.f;
    float dx = 0.f, dy = 0.f, dz = 0.f, dw = 0.f;
    int p = beg;
    GATHER8(esrc, y2)
    ushort4 us = *(const ushort4*)&y2[(size_t)n * 32 + l * 4];   // self (eps=0)
    float u0 = (ax + bx) + (cx + dx) + bf2f(us.x) + b2a[l * 4 + 0];
    float u1 = (ay + by) + (cy + dy) + bf2f(us.y) + b2a[l * 4 + 1];
    float u2 = (az + bz) + (cz + dz) + bf2f(us.z) + b2a[l * 4 + 2];
    float u3 = (aw + bw) + (cw + dw) + bf2f(us.w) + b2a[l * 4 + 3];
    u0 = u0 > 0.f ? u0 : 0.f;
    u1 = u1 > 0.f ? u1 : 0.f;
    u2 = u2 > 0.f ? u2 : 0.f;
    u3 = u3 > 0.f ? u3 : 0.f;

    float4 w4 = *(const float4*)&wc2[l * 4];
    float s = u0 * w4.x + u1 * w4.y + u2 * w4.z + u3 * w4.w;
    s += __shfl_xor(s, 1);
    s += __shfl_xor(s, 2);
    s += __shfl_xor(s, 4);
    if (l == 0) sbuf[n] = s + *c0;
}

// ---------------- layer3: scalar aggregate ----------------
__global__ __launch_bounds__(256) void final_kernel(const float* __restrict__ sbuf,
                                                    const int* __restrict__ rowbeg,
                                                    const int* __restrict__ rowend,
                                                    const int* __restrict__ esrc,
                                                    const float* __restrict__ b3,
                                                    float* __restrict__ out) {
    int n = blockIdx.x * 256 + threadIdx.x;
    if (n >= NN) return;
    float v = sbuf[n] + b3[0];
    int beg = rowbeg[n], end = rowend[n];
    int p = beg;
    for (; p + 4 <= end; p += 4) {
        int s0 = esrc[p], s1 = esrc[p + 1], s2 = esrc[p + 2], s3 = esrc[p + 3];
        float g0 = sbuf[s0], g1 = sbuf[s1], g2 = sbuf[s2], g3 = sbuf[s3];
        v += g0; v += g1; v += g2; v += g3;
    }
    for (; p < end; p++) v += sbuf[esrc[p]];
    out[n] = v;
}

// ---------------- host ----------------
extern "C" void kernel_launch(void* const* d_in, const int* in_sizes, int n_in,
                              void* d_out, int out_size, void* d_ws, size_t ws_size,
                              hipStream_t stream) {
    const float* x   = (const float*)d_in[0];
    const void*  ei  = d_in[1];
    const float* w1a = (const float*)d_in[2];
    const float* b1a = (const float*)d_in[3];
    const float* w1b = (const float*)d_in[4];
    const float* b1b = (const float*)d_in[5];
    const float* w2a = (const float*)d_in[6];
    const float* b2a = (const float*)d_in[7];
    const float* w2b = (const float*)d_in[8];
    const float* b2b = (const float*)d_in[9];
    const float* w3  = (const float*)d_in[10];
    const float* b3  = (const float*)d_in[11];
    float* out = (float*)d_out;

    char* w = (char*)d_ws;
    ushort_t*     y1      = (ushort_t*)(w + 0);             //  6,400,000
    ushort_t*     y2      = (ushort_t*)(w + 6400000);       //  6,400,000
    int*          esrc    = (int*)     (w + 12800000);      //  8,007,680 (NB*BCAP*4)
    int*          rowbeg  = (int*)     (w + 20807680);      //    400,000
    int*          rowend  = (int*)     (w + 21207680);      //    400,000
    float*        sbuf    = (float*)   (w + 21607680);      //    400,000
    int*          gcursor = (int*)     (w + 22007680);      //     50,048 (NB*CPAD*4, line-padded)
    int*          flag    = (int*)     (w + 22057728);      //         16
    float*        Wc      = (float*)   (w + 22057744);      //      4,096
    float*        bc1     = (float*)   (w + 22061840);      //        128
    float*        wc2     = (float*)   (w + 22061968);      //        128
    float*        c0      = (float*)   (w + 22062096);      //         48 (pad to 22062144)
    unsigned int* binned  = (unsigned int*)(w + 22062144);  //  8,007,680 -> ends 30,069,824
    ushort_t*     Bfrag   = (ushort_t*)(w + 30069824);      //      8,192 -> ends 30,078,016

    setup_kernel<<<3, 1024, 0, stream>>>(ei, w1a, w1b, b1b, w2a, w2b, b2b, w3,
                                         flag, gcursor, Wc, bc1, wc2, c0, Bfrag);
    proj_bin_kernel<<<NBA + NPJ, 512, 0, stream>>>(x, Bfrag, y1, ei, flag, gcursor, binned);

    csr_agg1_kernel<<<NB, 512, 0, stream>>>(binned, gcursor, y1, b1a, Wc, bc1,
                                            rowbeg, rowend, esrc, y2);
    agg_mlp2_kernel<<<NN / 32, 256, 0, stream>>>(y2, rowbeg, rowend, esrc, b2a, wc2, c0, sbuf);

    final_kernel<<<(NN + 255) / 256, 256, 0, stream>>>(sbuf, rowbeg, rowend, esrc, b3, out);
}

// Round 22
// 99.728 us; speedup vs baseline: 2.0200x; 2.0200x over previous
//
#include <hip/hip_runtime.h>

#define NN 100000
#define NE 1600000
#define IC 128
#define HID 32
#define NB 782           // buckets of 128 nodes
#define BCAP 2560        // padded bucket capacity (mean 2048, sigma~45)
#define EB 8192          // edges per binning block (amortize per-block NB-fixed cost)
#define NBA 196          // ceil(NE/EB)
#define NPJ 782          // ceil(NN/128) proj blocks (128 nodes each, 8 waves)

typedef unsigned short ushort_t;
typedef __attribute__((ext_vector_type(8))) short short8v;
typedef __attribute__((ext_vector_type(4))) float f32x4;

__device__ __forceinline__ ushort_t f2bf(float x) {
    unsigned u = __float_as_uint(x);
    unsigned r = (u + 0x7fffu + ((u >> 16) & 1u)) >> 16;   // RNE
    return (ushort_t)r;
}
__device__ __forceinline__ float bf2f(ushort_t b) {
    return __uint_as_float(((unsigned)b) << 16);
}

__device__ __forceinline__ int edge_at(const void* ei, int i64f, long long idx) {
    return i64f ? (int)((const long long*)ei)[idx] : ((const int*)ei)[idx];
}

// 8-deep independent-load gather step (lane l owns features 4l..4l+3)
#define GATHER8(SRC, Y)                                                            \
    for (; p + 8 <= end; p += 8) {                                                 \
        int s0 = SRC[p],     s1 = SRC[p + 1], s2 = SRC[p + 2], s3 = SRC[p + 3];    \
        int s4 = SRC[p + 4], s5 = SRC[p + 5], s6 = SRC[p + 6], s7 = SRC[p + 7];    \
        ushort4 u0 = *(const ushort4*)&Y[(size_t)s0 * 32 + l * 4];                 \
        ushort4 u1 = *(const ushort4*)&Y[(size_t)s1 * 32 + l * 4];                 \
        ushort4 u2 = *(const ushort4*)&Y[(size_t)s2 * 32 + l * 4];                 \
        ushort4 u3 = *(const ushort4*)&Y[(size_t)s3 * 32 + l * 4];                 \
        ushort4 u4 = *(const ushort4*)&Y[(size_t)s4 * 32 + l * 4];                 \
        ushort4 u5 = *(const ushort4*)&Y[(size_t)s5 * 32 + l * 4];                 \
        ushort4 u6 = *(const ushort4*)&Y[(size_t)s6 * 32 + l * 4];                 \
        ushort4 u7 = *(const ushort4*)&Y[(size_t)s7 * 32 + l * 4];                 \
        ax += bf2f(u0.x); ay += bf2f(u0.y); az += bf2f(u0.z); aw += bf2f(u0.w);    \
        bx += bf2f(u1.x); by += bf2f(u1.y); bz += bf2f(u1.z); bw += bf2f(u1.w);    \
        cx += bf2f(u2.x); cy += bf2f(u2.y); cz += bf2f(u2.z); cw += bf2f(u2.w);    \
        dx += bf2f(u3.x); dy += bf2f(u3.y); dz += bf2f(u3.z); dw += bf2f(u3.w);    \
        ax += bf2f(u4.x); ay += bf2f(u4.y); az += bf2f(u4.z); aw += bf2f(u4.w);    \
        bx += bf2f(u5.x); by += bf2f(u5.y); bz += bf2f(u5.z); bw += bf2f(u5.w);    \
        cx += bf2f(u6.x); cy += bf2f(u6.y); cz += bf2f(u6.z); cw += bf2f(u6.w);    \
        dx += bf2f(u7.x); dy += bf2f(u7.y); dz += bf2f(u7.z); dw += bf2f(u7.w);    \
    }                                                                              \
    for (; p + 4 <= end; p += 4) {                                                 \
        int s0 = SRC[p], s1 = SRC[p + 1], s2 = SRC[p + 2], s3 = SRC[p + 3];        \
        ushort4 u0 = *(const ushort4*)&Y[(size_t)s0 * 32 + l * 4];                 \
        ushort4 u1 = *(const ushort4*)&Y[(size_t)s1 * 32 + l * 4];                 \
        ushort4 u2 = *(const ushort4*)&Y[(size_t)s2 * 32 + l * 4];                 \
        ushort4 u3 = *(const ushort4*)&Y[(size_t)s3 * 32 + l * 4];                 \
        ax += bf2f(u0.x); ay += bf2f(u0.y); az += bf2f(u0.z); aw += bf2f(u0.w);    \
        bx += bf2f(u1.x); by += bf2f(u1.y); bz += bf2f(u1.z); bw += bf2f(u1.w);    \
        cx += bf2f(u2.x); cy += bf2f(u2.y); cz += bf2f(u2.z); cw += bf2f(u2.w);    \
        dx += bf2f(u3.x); dy += bf2f(u3.y); dz += bf2f(u3.z); dw += bf2f(u3.w);    \
    }                                                                              \
    for (; p < end; p++) {                                                         \
        ushort4 u0 = *(const ushort4*)&Y[(size_t)SRC[p] * 32 + l * 4];             \
        ax += bf2f(u0.x); ay += bf2f(u0.y); az += bf2f(u0.z); aw += bf2f(u0.w);    \
    }

// ---------------- setup: detect + folded weights + cursors + w1a MFMA B-fragments ----------------
__global__ __launch_bounds__(1024) void setup_kernel(const void* ei, const float* __restrict__ w1a,
                                                     const float* __restrict__ w1b, const float* __restrict__ b1b,
                                                     const float* __restrict__ w2a, const float* __restrict__ w2b,
                                                     const float* __restrict__ b2b, const float* __restrict__ w3,
                                                     int* flag, int* gcursor,
                                                     float* Wc, float* bc1, float* wc2, float* c0,
                                                     ushort_t* Bfrag) {
    int t = threadIdx.x;
    if (blockIdx.x == 1) {
        if (t < NB) gcursor[t] = 0;
        return;
    }
    if (blockIdx.x == 2) {
        if (t < 512) {
            int s = t >> 7, u = (t >> 6) & 1, l = t & 63;
            int krow = s * 32 + (l >> 4) * 8;
            int col = u * 16 + (l & 15);
            #pragma unroll
            for (int j = 0; j < 8; j++)
                Bfrag[t * 8 + j] = f2bf(w1a[(krow + j) * 32 + col]);
        }
        return;
    }
    if (t < 64) {
        const long long* p = (const long long*)ei;
        long long v = p[t];
        unsigned long long bad = __ballot(v < 0 || v >= NN);
        if (t == 0) *flag = (bad == 0ull) ? 1 : 0;
    }
    int k = t >> 5, j = t & 31;
    float acc = 0.f;
    for (int m = 0; m < HID; m++) acc += w1b[k * HID + m] * w2a[m * HID + j];
    Wc[k * HID + j] = acc;
    if (t < 32) {
        float a = 0.f;
        for (int m = 0; m < HID; m++) a += b1b[m] * w2a[m * HID + t];
        bc1[t] = a;
    } else if (t < 64) {
        int kk = t - 32;
        float a = 0.f;
        for (int jj = 0; jj < HID; jj++) a += w2b[kk * HID + jj] * w3[jj];
        wc2[kk] = a;
    } else if (t == 64) {
        float a = 0.f;
        for (int jj = 0; jj < HID; jj++) a += b2b[jj] * w3[jj];
        *c0 = a;
    }
}

// ---------------- binscatter (EB=8192, dst-only staging) + MFMA proj merged ----------------
// LDS: bktdl[8192] 32KB + hh/lcur 6.3KB = 38.3KB -> 4 blocks/CU.
__global__ __launch_bounds__(512) void proj_bin_kernel(const float* __restrict__ x,
                                                       const ushort_t* __restrict__ Bfrag,
                                                       ushort_t* __restrict__ y1,
                                                       const void* ei, const int* flag,
                                                       int* gcursor,
                                                       unsigned int* __restrict__ binned) {
    __shared__ int bktdl[EB];          // staged dst (or -1)
    __shared__ int hh[NB];
    __shared__ int lcur[NB];
    int t = threadIdx.x;

    if (blockIdx.x < NBA) {
        // ---- binscatter: hist (stage dst), reserve, scatter (re-read src stream) ----
        int bb = blockIdx.x;
        for (int b = t; b < NB; b += 512) hh[b] = 0;
        __syncthreads();
        int i64f = *flag;
        long long ebase = (long long)bb * EB;
        #pragma unroll
        for (int q = 0; q < EB / 512; q++) {
            int i = q * 512 + t;
            long long e = ebase + i;
            int d = -1;
            if (e < NE) {
                d = edge_at(ei, i64f, NE + e);
                atomicAdd(&hh[d >> 7], 1);
            }
            bktdl[i] = d;
        }
        __syncthreads();
        for (int b = t; b < NB; b += 512)
            lcur[b] = hh[b] ? atomicAdd(&gcursor[b], hh[b]) : 0;
        __syncthreads();
        #pragma unroll
        for (int q = 0; q < EB / 512; q++) {
            int i = q * 512 + t;
            int d = bktdl[i];
            if (d >= 0) {
                int s = edge_at(ei, i64f, ebase + i);
                int b = d >> 7;
                int pos = atomicAdd(&lcur[b], 1);
                binned[(size_t)b * BCAP + pos] = ((unsigned)s << 7) | (unsigned)(d & 127);
            }
        }
    } else {
        // ---- MFMA proj: y1 = bf16(x @ w1a). 8 waves x 16 nodes = 128 nodes/block ----
        int pb = blockIdx.x - NBA;
        int wv = t >> 6, l = t & 63;
        int base = pb * 128 + wv * 16;
        int row = l & 15;
        int kg = l >> 4;                 // 0..3
        size_t m = (size_t)(base + row);
        if (m >= NN) m = NN - 1;         // clamp (last block): result discarded
        const float* xr = x + m * 128 + kg * 8;

        f32x4 acc0 = {0.f, 0.f, 0.f, 0.f};
        f32x4 acc1 = {0.f, 0.f, 0.f, 0.f};
        #pragma unroll
        for (int s = 0; s < 4; s++) {
            float4 xa = *(const float4*)(xr + s * 32);
            float4 xb = *(const float4*)(xr + s * 32 + 4);
            short8v af;
            af[0] = (short)f2bf(xa.x); af[1] = (short)f2bf(xa.y);
            af[2] = (short)f2bf(xa.z); af[3] = (short)f2bf(xa.w);
            af[4] = (short)f2bf(xb.x); af[5] = (short)f2bf(xb.y);
            af[6] = (short)f2bf(xb.z); af[7] = (short)f2bf(xb.w);
            short8v b0 = *(const short8v*)&Bfrag[((s * 2 + 0) * 64 + l) * 8];
            short8v b1 = *(const short8v*)&Bfrag[((s * 2 + 1) * 64 + l) * 8];
            acc0 = __builtin_amdgcn_mfma_f32_16x16x32_bf16(af, b0, acc0, 0, 0, 0);
            acc1 = __builtin_amdgcn_mfma_f32_16x16x32_bf16(af, b1, acc1, 0, 0, 0);
        }
        // D: col = l&15, row = (l>>4)*4 + reg   [m89 verified]
        int col = l & 15;
        #pragma unroll
        for (int r = 0; r < 4; r++) {
            int node = base + kg * 4 + r;
            if (node < NN) {
                y1[(size_t)node * 32 + col]      = f2bf(acc0[r]);
                y1[(size_t)node * 32 + 16 + col] = f2bf(acc1[r]);
            }
        }
    }
}

// ---------------- csr_agg1: per-bucket CSR sort + layer-1 gather + fused MLP, 512 thr ----------------
__global__ __launch_bounds__(512) void csr_agg1_kernel(const unsigned int* __restrict__ binned,
                                                       const int* __restrict__ gcursor,
                                                       const ushort_t* __restrict__ y1,
                                                       const float* __restrict__ b1a,
                                                       const float* __restrict__ Wc,
                                                       const float* __restrict__ bc1,
                                                       int* __restrict__ rowbeg,
                                                       int* __restrict__ rowend,
                                                       int* __restrict__ esrc,
                                                       ushort_t* __restrict__ y2) {
    __shared__ int cnt[128];
    __shared__ int sc[128];
    __shared__ int cur[128];
    __shared__ int esl[BCAP];          // 10,240 B
    __shared__ float Wl[HID * HID];    //  4,096 B
    __shared__ float ul[128 * 36];     // 18,432 B   (total ~34.3 KB -> 4 blocks/CU)
    int t = threadIdx.x;
    int b = blockIdx.x;
    int n_edges = gcursor[b];
    int bbase = b * BCAP;

    Wl[t] = Wc[t];
    Wl[512 + t] = Wc[512 + t];
    if (t < 128) cnt[t] = 0;
    __syncthreads();
    for (int p = t; p < n_edges; p += 512)
        atomicAdd(&cnt[binned[bbase + p] & 127], 1);
    __syncthreads();
    if (t < 128) sc[t] = cnt[t];
    __syncthreads();
    for (int off = 1; off < 128; off <<= 1) {
        int a = 0;
        if (t < 128 && t >= off) a = sc[t - off];
        __syncthreads();
        if (t < 128) sc[t] += a;
        __syncthreads();
    }
    if (t < 128) {
        int excl = sc[t] - cnt[t];
        cur[t] = excl;
        int gn = (b << 7) + t;
        if (gn < NN) { rowbeg[gn] = bbase + excl; rowend[gn] = bbase + excl + cnt[t]; }
    }
    __syncthreads();
    for (int p = t; p < n_edges; p += 512) {
        unsigned wv = binned[bbase + p];
        int dl = wv & 127;
        int pos = atomicAdd(&cur[dl], 1);
        int src = (int)(wv >> 7);
        esl[pos] = src;
        esrc[bbase + pos] = src;       // persist for layers 2/3
    }
    __syncthreads();

    // ---- phase 2: gather + relu, 2 chunks of 64 nodes ----
    int gg = t >> 3;                   // 0..63
    int l = t & 7;
    #pragma unroll
    for (int chunk = 0; chunk < 2; chunk++) {
        int g = chunk * 64 + gg;
        int gn = (b << 7) + g;
        int beg = sc[g] - cnt[g];
        int end = sc[g];
        float ax = 0.f, ay = 0.f, az = 0.f, aw = 0.f;
        float bx = 0.f, by = 0.f, bz = 0.f, bw = 0.f;
        float cx = 0.f, cy = 0.f, cz = 0.f, cw = 0.f;
        float dx = 0.f, dy = 0.f, dz = 0.f, dw = 0.f;
        int p = beg;
        GATHER8(esl, y1)
        if (gn < NN) {
            ushort4 us = *(const ushort4*)&y1[(size_t)gn * 32 + l * 4];   // self (eps=0)
            float u0 = (ax + bx) + (cx + dx) + bf2f(us.x) + b1a[l * 4 + 0];
            float u1 = (ay + by) + (cy + dy) + bf2f(us.y) + b1a[l * 4 + 1];
            float u2 = (az + bz) + (cz + dz) + bf2f(us.z) + b1a[l * 4 + 2];
            float u3 = (aw + bw) + (cw + dw) + bf2f(us.w) + b1a[l * 4 + 3];
            u0 = u0 > 0.f ? u0 : 0.f;
            u1 = u1 > 0.f ? u1 : 0.f;
            u2 = u2 > 0.f ? u2 : 0.f;
            u3 = u3 > 0.f ? u3 : 0.f;
            *(float4*)&ul[g * 36 + l * 4] = make_float4(u0, u1, u2, u3);
        }
    }
    __syncthreads();
    #pragma unroll
    for (int chunk = 0; chunk < 2; chunk++) {
        int g = chunk * 64 + gg;
        int gn = (b << 7) + g;
        if (gn < NN) {
            float4 acc = *(const float4*)&bc1[l * 4];
            #pragma unroll
            for (int k = 0; k < HID; k++) {
                float uk = ul[g * 36 + k];
                float4 wv = *(const float4*)&Wl[k * HID + l * 4];
                acc.x += uk * wv.x; acc.y += uk * wv.y;
                acc.z += uk * wv.z; acc.w += uk * wv.w;
            }
            ushort4 ov;
            ov.x = f2bf(acc.x); ov.y = f2bf(acc.y); ov.z = f2bf(acc.z); ov.w = f2bf(acc.w);
            *(ushort4*)&y2[(size_t)gn * 32 + l * 4] = ov;
        }
    }
}

// ---------------- agg_mlp2: 8-lane gather (8-deep ILP) + fused relu/dot -> sbuf ----------------
__global__ __launch_bounds__(256) void agg_mlp2_kernel(const ushort_t* __restrict__ y2,
                                                       const int* __restrict__ rowbeg,
                                                       const int* __restrict__ rowend,
                                                       const int* __restrict__ esrc,
                                                       const float* __restrict__ b2a,
                                                       const float* __restrict__ wc2,
                                                       const float* __restrict__ c0,
                                                       float* __restrict__ sbuf) {
    int t = threadIdx.x;
    int g = t >> 3;
    int l = t & 7;
    int n = blockIdx.x * 32 + g;

    int beg = rowbeg[n], end = rowend[n];
    float ax = 0.f, ay = 0.f, az = 0.f, aw = 0.f;
    float bx = 0.f, by = 0.f, bz = 0.f, bw = 0.f;
    float cx = 0.f, cy = 0.f, cz = 0.f, cw = 0.f;
    float dx = 0.f, dy = 0.f, dz = 0.f, dw = 0.f;
    int p = beg;
    GATHER8(esrc, y2)
    ushort4 us = *(const ushort4*)&y2[(size_t)n * 32 + l * 4];   // self (eps=0)
    float u0 = (ax + bx) + (cx + dx) + bf2f(us.x) + b2a[l * 4 + 0];
    float u1 = (ay + by) + (cy + dy) + bf2f(us.y) + b2a[l * 4 + 1];
    float u2 = (az + bz) + (cz + dz) + bf2f(us.z) + b2a[l * 4 + 2];
    float u3 = (aw + bw) + (cw + dw) + bf2f(us.w) + b2a[l * 4 + 3];
    u0 = u0 > 0.f ? u0 : 0.f;
    u1 = u1 > 0.f ? u1 : 0.f;
    u2 = u2 > 0.f ? u2 : 0.f;
    u3 = u3 > 0.f ? u3 : 0.f;

    float4 w4 = *(const float4*)&wc2[l * 4];
    float s = u0 * w4.x + u1 * w4.y + u2 * w4.z + u3 * w4.w;
    s += __shfl_xor(s, 1);
    s += __shfl_xor(s, 2);
    s += __shfl_xor(s, 4);
    if (l == 0) sbuf[n] = s + *c0;
}

// ---------------- layer3: scalar aggregate ----------------
__global__ __launch_bounds__(256) void final_kernel(const float* __restrict__ sbuf,
                                                    const int* __restrict__ rowbeg,
                                                    const int* __restrict__ rowend,
                                                    const int* __restrict__ esrc,
                                                    const float* __restrict__ b3,
                                                    float* __restrict__ out) {
    int n = blockIdx.x * 256 + threadIdx.x;
    if (n >= NN) return;
    float v = sbuf[n] + b3[0];
    int beg = rowbeg[n], end = rowend[n];
    int p = beg;
    for (; p + 4 <= end; p += 4) {
        int s0 = esrc[p], s1 = esrc[p + 1], s2 = esrc[p + 2], s3 = esrc[p + 3];
        float g0 = sbuf[s0], g1 = sbuf[s1], g2 = sbuf[s2], g3 = sbuf[s3];
        v += g0; v += g1; v += g2; v += g3;
    }
    for (; p < end; p++) v += sbuf[esrc[p]];
    out[n] = v;
}

// ---------------- host ----------------
extern "C" void kernel_launch(void* const* d_in, const int* in_sizes, int n_in,
                              void* d_out, int out_size, void* d_ws, size_t ws_size,
                              hipStream_t stream) {
    const float* x   = (const float*)d_in[0];
    const void*  ei  = d_in[1];
    const float* w1a = (const float*)d_in[2];
    const float* b1a = (const float*)d_in[3];
    const float* w1b = (const float*)d_in[4];
    const float* b1b = (const float*)d_in[5];
    const float* w2a = (const float*)d_in[6];
    const float* b2a = (const float*)d_in[7];
    const float* w2b = (const float*)d_in[8];
    const float* b2b = (const float*)d_in[9];
    const float* w3  = (const float*)d_in[10];
    const float* b3  = (const float*)d_in[11];
    float* out = (float*)d_out;

    char* w = (char*)d_ws;
    ushort_t*     y1      = (ushort_t*)(w + 0);             //  6,400,000
    ushort_t*     y2      = (ushort_t*)(w + 6400000);       //  6,400,000
    int*          esrc    = (int*)     (w + 12800000);      //  8,007,680 (NB*BCAP*4)
    int*          rowbeg  = (int*)     (w + 20807680);      //    400,000
    int*          rowend  = (int*)     (w + 21207680);      //    400,000
    float*        sbuf    = (float*)   (w + 21607680);      //    400,000
    int*          gcursor = (int*)     (w + 22007680);      //      3,136
    int*          flag    = (int*)     (w + 22010816);      //         16
    float*        Wc      = (float*)   (w + 22010832);      //      4,096
    float*        bc1     = (float*)   (w + 22014928);      //        128
    float*        wc2     = (float*)   (w + 22015056);      //        128
    float*        c0      = (float*)   (w + 22015184);      //         48 (pad to 22015232)
    unsigned int* binned  = (unsigned int*)(w + 22015232);  //  8,007,680 -> ends 30,022,912
    ushort_t*     Bfrag   = (ushort_t*)(w + 30022912);      //      8,192 -> ends 30,031,104

    setup_kernel<<<3, 1024, 0, stream>>>(ei, w1a, w1b, b1b, w2a, w2b, b2b, w3,
                                         flag, gcursor, Wc, bc1, wc2, c0, Bfrag);
    proj_bin_kernel<<<NBA + NPJ, 512, 0, stream>>>(x, Bfrag, y1, ei, flag, gcursor, binned);

    csr_agg1_kernel<<<NB, 512, 0, stream>>>(binned, gcursor, y1, b1a, Wc, bc1,
                                            rowbeg, rowend, esrc, y2);
    agg_mlp2_kernel<<<NN / 32, 256, 0, stream>>>(y2, rowbeg, rowend, esrc, b2a, wc2, c0, sbuf);

    final_kernel<<<(NN + 255) / 256, 256, 0, stream>>>(sbuf, rowbeg, rowend, esrc, b3, out);
}